// Round 9
// baseline (531.908 us; speedup 1.0000x reference)
//
#include <hip/hip_runtime.h>
#include <math.h>

#define DD 512
#define MM 512
#define BB 32
#define TT 4
#define VV 32000
#define BV ((size_t)BB * VV)
#define QN 8000                       // vocab quarter per wscatter block
#define NCHUNK 250                    // wsumV row-chunks (128 rows each)

// ---- weight builder: accW[b][v] = sum_{(m,t): story[b,m,t]==v} w[b][m]
// w = softmax(s[b]) (or 1/M if s==null). Grid (4, B): block = (quarter q, b).
// Scatter goes into block-private LDS (no global atomics), then plain stores.
__global__ __launch_bounds__(256) void wscatter_kernel(const float* __restrict__ s,
                                                       const int* __restrict__ story,
                                                       float* __restrict__ accW) {
  __shared__ float accl[QN];
  __shared__ float wsm[MM];
  __shared__ float red[16];
  int q = blockIdx.x, b = blockIdx.y;
  int t = threadIdx.x;
  int lo = q * QN, hi = lo + QN;
  if (s) {
    float v0 = s[b * MM + t], v1 = s[b * MM + t + 256];
    float mx = fmaxf(v0, v1);
#pragma unroll
    for (int off = 32; off > 0; off >>= 1) mx = fmaxf(mx, __shfl_xor(mx, off));
    if ((t & 63) == 0) red[t >> 6] = mx;
    __syncthreads();
    mx = fmaxf(fmaxf(red[0], red[1]), fmaxf(red[2], red[3]));
    float e0 = expf(v0 - mx), e1 = expf(v1 - mx);
    float sm = e0 + e1;
#pragma unroll
    for (int off = 32; off > 0; off >>= 1) sm += __shfl_xor(sm, off);
    if ((t & 63) == 0) red[8 + (t >> 6)] = sm;
    __syncthreads();
    sm = red[8] + red[9] + red[10] + red[11];
    float inv = 1.0f / sm;
    wsm[t] = e0 * inv;
    wsm[t + 256] = e1 * inv;
  } else {
    wsm[t] = 1.0f / MM;
    wsm[t + 256] = 1.0f / MM;
  }
  for (int i = t; i < QN; i += 256) accl[i] = 0.f;
  __syncthreads();
  const int* stb = story + (size_t)b * MM * TT;
#pragma unroll
  for (int j = 0; j < 8; ++j) {             // 2048 entries, coalesced
    int e = j * 256 + t;
    int v = stb[e];
    if (v >= lo && v < hi) atomicAdd(&accl[v - lo], wsm[e >> 2]);
  }
  __syncthreads();
  float* ob = accW + (size_t)b * VV + lo;
  for (int i = t; i < QN; i += 256) ob[i] = accl[i];
}

// ---- dense weighted column-sum: part[chunk][b][d] = sum_{v in chunk} W[b][v]*C[v][d]
// 250 blocks x 512 threads (thread = d), 128 rows per chunk; pure streaming.
__global__ __launch_bounds__(512) void wsumV_kernel(const float* __restrict__ table,
                                                    const float* __restrict__ W,
                                                    float* __restrict__ part) {
  __shared__ float wsh[128 * 33];
  int v0 = blockIdx.x << 7;
  int t = threadIdx.x;
#pragma unroll
  for (int k = 0; k < 8; ++k) {             // stage W[b][v0..v0+128) -> wsh[v*33+b]
    int idx = (k << 9) + t;
    int b = idx >> 7, v = idx & 127;
    wsh[v * 33 + b] = W[(size_t)b * VV + v0 + v];
  }
  __syncthreads();
  float acc[32];
#pragma unroll
  for (int b = 0; b < 32; ++b) acc[b] = 0.f;
  const float* tp = table + (size_t)v0 * DD + t;
  float r = tp[0];
  for (int v = 0; v < 128; ++v) {
    float rn = (v < 127) ? tp[(size_t)(v + 1) * DD] : 0.f;  // prefetch next row
#pragma unroll
    for (int b = 0; b < 32; ++b) acc[b] += wsh[v * 33 + b] * r;
    r = rn;
  }
  float* pp = part + (size_t)blockIdx.x * (32 * DD) + t;
#pragma unroll
  for (int b = 0; b < 32; ++b) pp[(size_t)b * DD] = acc[b];
}

// ---- uout[b][d] = (prev?prev:0) + sum_{c<250} part[c][b][d]
__global__ void reduceV_kernel(const float* __restrict__ part,
                               const float* __restrict__ prev,
                               float* __restrict__ uout) {
  int i = blockIdx.x * 256 + threadIdx.x;   // 64 blocks -> B*D
  float acc = 0.f;
  for (int c = 0; c < NCHUNK; ++c) acc += part[(size_t)c * 16384 + i];
  uout[i] = (prev ? prev[i] : 0.f) + acc;
}

// ---- decoder hop0 variant: o = sum part; uk = hid + o; hc = [hid | o]
__global__ void reduceV2_kernel(const float* __restrict__ part,
                                const float* __restrict__ hid,
                                float* __restrict__ uk, float* __restrict__ hc) {
  int i = blockIdx.x * 256 + threadIdx.x;
  int b = i >> 9, d = i & 511;
  float o = 0.f;
  for (int c = 0; c < NCHUNK; ++c) o += part[(size_t)c * 16384 + i];
  float hv = hid[i];
  uk[i] = hv + o;
  hc[b * 1024 + d] = hv;
  hc[b * 1024 + 512 + d] = o;
}

// ---- fused gather + dot: s[p] = (sum_t table[story[p,t]]) . u[b]. One wave per p.
__global__ __launch_bounds__(256) void pooldot_kernel(const float* __restrict__ table,
                                                      const int* __restrict__ story,
                                                      const float* __restrict__ u,
                                                      float* __restrict__ s) {
  int wave = (blockIdx.x << 2) + (threadIdx.x >> 6);
  int lane = threadIdx.x & 63;
  int b = wave >> 9;
  const int* st = story + wave * TT;
  size_t r0 = (size_t)st[0] * DD, r1 = (size_t)st[1] * DD;
  size_t r2 = (size_t)st[2] * DD, r3 = (size_t)st[3] * DD;
  const float4* t4 = (const float4*)table;
  const float4* ur = (const float4*)(u + (size_t)b * DD);
  float acc = 0.f;
#pragma unroll
  for (int h = 0; h < 2; ++h) {
    int c = (h << 6) + lane;
    float4 a = t4[(r0 >> 2) + c];
    float4 bb = t4[(r1 >> 2) + c];
    float4 cc = t4[(r2 >> 2) + c];
    float4 d = t4[(r3 >> 2) + c];
    float4 q = ur[c];
    acc += (a.x + bb.x + cc.x + d.x) * q.x;
    acc += (a.y + bb.y + cc.y + d.y) * q.y;
    acc += (a.z + bb.z + cc.z + d.z) * q.z;
    acc += (a.w + bb.w + cc.w + d.w) * q.w;
  }
#pragma unroll
  for (int off = 32; off > 0; off >>= 1) acc += __shfl_xor(acc, off);
  if (lane == 0) s[wave] = acc;
}

// ---- out[b][j] = bias[j] + W[j] . (vin ? vin[b] : table[q[b]]). One wave per (b,j).
__global__ __launch_bounds__(256) void matvec_kernel(const float* __restrict__ W,
                                                     const float* __restrict__ bias,
                                                     const float* __restrict__ vin,
                                                     const int* __restrict__ q,
                                                     const float* __restrict__ table,
                                                     float* __restrict__ out) {
  int idx = (blockIdx.x << 2) + (threadIdx.x >> 6);  // b*1536 + j
  int lane = threadIdx.x & 63;
  int b = idx / 1536;
  int j = idx - b * 1536;
  const float* xb = vin ? (vin + (size_t)b * DD) : (table + (size_t)q[b] * DD);
  const float4* Wr = (const float4*)(W + (size_t)j * DD);
  const float4* xr = (const float4*)xb;
  float acc = 0.f;
#pragma unroll
  for (int h = 0; h < 2; ++h) {
    int c = (h << 6) + lane;
    float4 a = Wr[c];
    float4 qv = xr[c];
    acc += a.x * qv.x + a.y * qv.y + a.z * qv.z + a.w * qv.w;
  }
#pragma unroll
  for (int off = 32; off > 0; off >>= 1) acc += __shfl_xor(acc, off);
  if (lane == 0) out[idx] = acc + bias[j];
}

// ---- GRU gates: hidden = (1-z)*n + z*u
__global__ void gate_kernel(const float* __restrict__ gi, const float* __restrict__ gh,
                            const float* __restrict__ u, float* __restrict__ hidden,
                            float* __restrict__ out_h) {
  int i = blockIdx.x * 256 + threadIdx.x;  // B*D
  int b = i >> 9, d = i & 511;
  const float* gib = gi + b * 1536;
  const float* ghb = gh + b * 1536;
  float i_r = gib[d], i_z = gib[d + 512], i_n = gib[d + 1024];
  float h_r = ghb[d], h_z = ghb[d + 512], h_n = ghb[d + 1024];
  float r = 1.f / (1.f + expf(-(i_r + h_r)));
  float z = 1.f / (1.f + expf(-(i_z + h_z)));
  float n = tanhf(i_n + r * h_n);
  float h = (1.f - z) * n + z * u[i];
  hidden[i] = h;
  out_h[i] = h;
}

// ---- p_vocab partials, split-K x2 (round-7 config): partc[kh][b][v]
__global__ __launch_bounds__(256) void pvocab_kernel(const float* __restrict__ Hcat,
                                                     const float* __restrict__ W1,
                                                     float* __restrict__ partc) {
  __shared__ float As[32][36];
  __shared__ float Bs[32][68];
  int t = threadIdx.x;
  int vt = blockIdx.x >> 1;
  int kh = blockIdx.x & 1;
  int v0 = vt * 64;
  int kbase = kh << 9;            // 0 or 512
  int tb = t >> 5;
  int tv = t & 31;
  int br = t >> 2;
  int bk = (t & 3) << 3;
  const float* Wp = W1 + (size_t)(v0 + br) * 1024 + kbase + bk;
  int ab = t >> 3;
  int ak = (t & 7) << 2;
  const float* Ap = Hcat + (size_t)ab * 1024 + kbase + ak;

  float acc[4][2] = {{0.f, 0.f}, {0.f, 0.f}, {0.f, 0.f}, {0.f, 0.f}};

  float4 aReg = *(const float4*)(Ap);
  float4 wReg0 = *(const float4*)(Wp);
  float4 wReg1 = *(const float4*)(Wp + 4);

  for (int k0 = 0; k0 < 512; k0 += 32) {
    As[ak + 0][ab] = aReg.x; As[ak + 1][ab] = aReg.y;
    As[ak + 2][ab] = aReg.z; As[ak + 3][ab] = aReg.w;
    Bs[bk + 0][br] = wReg0.x; Bs[bk + 1][br] = wReg0.y;
    Bs[bk + 2][br] = wReg0.z; Bs[bk + 3][br] = wReg0.w;
    Bs[bk + 4][br] = wReg1.x; Bs[bk + 5][br] = wReg1.y;
    Bs[bk + 6][br] = wReg1.z; Bs[bk + 7][br] = wReg1.w;
    __syncthreads();
    if (k0 + 32 < 512) {
      aReg = *(const float4*)(Ap + k0 + 32);
      wReg0 = *(const float4*)(Wp + k0 + 32);
      wReg1 = *(const float4*)(Wp + k0 + 36);
    }
#pragma unroll
    for (int k = 0; k < 32; ++k) {
      float2 bv = *(const float2*)&Bs[k][tv * 2];
      float4 av = *(const float4*)&As[k][tb * 4];
      acc[0][0] += av.x * bv.x; acc[0][1] += av.x * bv.y;
      acc[1][0] += av.y * bv.x; acc[1][1] += av.y * bv.y;
      acc[2][0] += av.z * bv.x; acc[2][1] += av.z * bv.y;
      acc[3][0] += av.w * bv.x; acc[3][1] += av.w * bv.y;
    }
    __syncthreads();
  }
  int v = v0 + tv * 2;
  float* base = partc + (size_t)kh * BV;
#pragma unroll
  for (int i = 0; i < 4; ++i) {
    float2 r;
    r.x = acc[i][0];
    r.y = acc[i][1];
    *(float2*)(base + (size_t)(tb * 4 + i) * VV + v) = r;
  }
}

// ---- out[b][v] = partc[0][b][v] + partc[1][b][v] + W1b[v].  grid (125, 32).
__global__ void pvreduce_kernel(const float* __restrict__ partc,
                                const float* __restrict__ W1b,
                                float* __restrict__ out) {
  int v = blockIdx.x * 256 + threadIdx.x;   // 125*256 = 32000
  int b = blockIdx.y;
  size_t o = (size_t)b * VV + v;
  out[o] = partc[o] + partc[BV + o] + W1b[v];
}

extern "C" void kernel_launch(void* const* d_in, const int* in_sizes, int n_in,
                              void* d_out, int out_size, void* d_ws, size_t ws_size,
                              hipStream_t stream) {
  const int* story = (const int*)d_in[0];
  const int* q = (const int*)d_in[1];
  const float* C_enc = (const float*)d_in[2];
  const float* C_dec = (const float*)d_in[3];
  const float* W_ih = (const float*)d_in[4];
  const float* W_hh = (const float*)d_in[5];
  const float* b_ih = (const float*)d_in[6];
  const float* b_hh = (const float*)d_in[7];
  const float* W1 = (const float*)d_in[8];
  const float* W1b = (const float*)d_in[9];
  float* out = (float*)d_out;

  const size_t VD = (size_t)VV * DD;
  const float* C1 = C_enc + 1 * VD;
  const float* C2 = C_enc + 2 * VD;
  const float* C3 = C_enc + 3 * VD;
  const float* D0 = C_dec + 0 * VD;
  const float* D1 = C_dec + 1 * VD;
  const float* D2 = C_dec + 2 * VD;

  float* accW = (float*)d_ws;                      // [B*V]
  float* part = accW + BV;                         // [250*32*512]
  float* partc = part + (size_t)NCHUNK * 32 * DD;  // [2*B*V]
  float* u = partc + 2 * BV;                       // [B*D]
  float* s = u + BB * DD;                          // [B*M]
  float* gi = s + BB * MM;                         // [B*3D]
  float* gh = gi + BB * 3 * DD;                    // [B*3D]
  float* hid = gh + BB * 3 * DD;                   // [B*D]
  float* uk = hid + BB * DD;                       // [B*D]
  float* hc = uk + BB * DD;                        // [B*2D]

  float* p_ptr_out = out;
  float* p_vocab_out = out + BB * MM;
  float* hid_out = out + BB * MM + (size_t)BB * VV;

  dim3 blk(256);
  const dim3 wsGrid(4, BB);            // wscatter: (quarter, b)
  const int pdGrid = BB * MM / 4;      // 4096 blocks x 4 waves
  const int mvGrid = BB * 3 * DD / 4;  // 3072 blocks
  const int ewGrid = BB * DD / 256;    // 64

  // ---------------- encoder (u0 = 0 => hop0 softmax uniform; C_enc[0] unused)
  wscatter_kernel<<<wsGrid, blk, 0, stream>>>(nullptr, story, accW);   // uniform
  wsumV_kernel<<<NCHUNK, dim3(512), 0, stream>>>(C1, accW, part);
  reduceV_kernel<<<ewGrid, blk, 0, stream>>>(part, nullptr, u);        // u1
  pooldot_kernel<<<pdGrid, blk, 0, stream>>>(C1, story, u, s);         // s1 (C1 L3-hot)
  wscatter_kernel<<<wsGrid, blk, 0, stream>>>(s, story, accW);
  wsumV_kernel<<<NCHUNK, dim3(512), 0, stream>>>(C2, accW, part);
  reduceV_kernel<<<ewGrid, blk, 0, stream>>>(part, u, u);              // u2
  pooldot_kernel<<<pdGrid, blk, 0, stream>>>(C2, story, u, s);         // s2 (C2 L3-hot)
  wscatter_kernel<<<wsGrid, blk, 0, stream>>>(s, story, accW);
  wsumV_kernel<<<NCHUNK, dim3(512), 0, stream>>>(C3, accW, part);
  reduceV_kernel<<<ewGrid, blk, 0, stream>>>(part, u, u);              // u3 = enc_hidden

  // ---------------- GRU step (embed folded into matvec_gi)
  matvec_kernel<<<mvGrid, blk, 0, stream>>>(W_ih, b_ih, nullptr, q, C_dec, gi);
  matvec_kernel<<<mvGrid, blk, 0, stream>>>(W_hh, b_hh, u, nullptr, nullptr, gh);
  gate_kernel<<<ewGrid, blk, 0, stream>>>(gi, gh, u, hid, hid_out);

  // ---------------- pointer decoder (C_dec[3] pooled is dead code)
  pooldot_kernel<<<pdGrid, blk, 0, stream>>>(D0, story, hid, s);       // hop0 logits
  wscatter_kernel<<<wsGrid, blk, 0, stream>>>(s, story, accW);
  wsumV_kernel<<<NCHUNK, dim3(512), 0, stream>>>(D1, accW, part);
  reduceV2_kernel<<<ewGrid, blk, 0, stream>>>(part, hid, uk, hc);      // o0, uk1, hcat
  pooldot_kernel<<<pdGrid, blk, 0, stream>>>(D1, story, uk, s);        // hop1 logits (D1 hot)
  wscatter_kernel<<<wsGrid, blk, 0, stream>>>(s, story, accW);
  wsumV_kernel<<<NCHUNK, dim3(512), 0, stream>>>(D2, accW, part);
  reduceV_kernel<<<ewGrid, blk, 0, stream>>>(part, uk, uk);            // uk2
  pooldot_kernel<<<pdGrid, blk, 0, stream>>>(D2, story, uk, p_ptr_out); // p_ptr (D2 hot)

  // ---------------- vocab projection (split-K x2 + reduce)
  pvocab_kernel<<<VV / 64 * 2, blk, 0, stream>>>(hc, W1, partc);
  pvreduce_kernel<<<dim3(125, 32), blk, 0, stream>>>(partc, W1b, p_vocab_out);
}

// Round 10
// 470.346 us; speedup vs baseline: 1.1309x; 1.1309x over previous
//
#include <hip/hip_runtime.h>
#include <math.h>

#define DD 512
#define MM 512
#define BB 32
#define TT 4
#define VV 32000
#define BV ((size_t)BB * VV)
#define QN 8000                       // vocab quarter per wscatter block
#define NCHUNK 250                    // wsumV v-chunks (128 rows each)

// ---- weight builder: accW[b][v] = sum_{(m,t): story[b,m,t]==v} w[b][m]
// w = softmax(s[b]) (or 1/M if s==null). Grid (4, B). LDS scatter, no global atomics.
__global__ __launch_bounds__(256) void wscatter_kernel(const float* __restrict__ s,
                                                       const int* __restrict__ story,
                                                       float* __restrict__ accW) {
  __shared__ float accl[QN];
  __shared__ float wsm[MM];
  __shared__ float red[16];
  int q = blockIdx.x, b = blockIdx.y;
  int t = threadIdx.x;
  int lo = q * QN, hi = lo + QN;
  if (s) {
    float v0 = s[b * MM + t], v1 = s[b * MM + t + 256];
    float mx = fmaxf(v0, v1);
#pragma unroll
    for (int off = 32; off > 0; off >>= 1) mx = fmaxf(mx, __shfl_xor(mx, off));
    if ((t & 63) == 0) red[t >> 6] = mx;
    __syncthreads();
    mx = fmaxf(fmaxf(red[0], red[1]), fmaxf(red[2], red[3]));
    float e0 = expf(v0 - mx), e1 = expf(v1 - mx);
    float sm = e0 + e1;
#pragma unroll
    for (int off = 32; off > 0; off >>= 1) sm += __shfl_xor(sm, off);
    if ((t & 63) == 0) red[8 + (t >> 6)] = sm;
    __syncthreads();
    sm = red[8] + red[9] + red[10] + red[11];
    float inv = 1.0f / sm;
    wsm[t] = e0 * inv;
    wsm[t + 256] = e1 * inv;
  } else {
    wsm[t] = 1.0f / MM;
    wsm[t + 256] = 1.0f / MM;
  }
  for (int i = t; i < QN; i += 256) accl[i] = 0.f;
  __syncthreads();
  const int* stb = story + (size_t)b * MM * TT;
#pragma unroll
  for (int j = 0; j < 8; ++j) {             // 2048 entries, coalesced
    int e = j * 256 + t;
    int v = stb[e];
    if (v >= lo && v < hi) atomicAdd(&accl[v - lo], wsm[e >> 2]);
  }
  __syncthreads();
  float* ob = accW + (size_t)b * VV + lo;
  for (int i = t; i < QN; i += 256) ob[i] = accl[i];
}

// ---- dense weighted column-sum, stream-structured.
// part[chunk][b][d] = sum_{v in chunk(128)} W[b][v] * C[v][d]
// grid 500: chunk = bid>>1, dhalf = bid&1; 256 threads (thread = one d column).
// Row loop unrolled x8 -> 8 independent loads in flight (hides HBM latency).
__global__ __launch_bounds__(256) void wsumV_kernel(const float* __restrict__ table,
                                                    const float* __restrict__ W,
                                                    float* __restrict__ part) {
  __shared__ float wsh[128][33];
  int chunk = blockIdx.x >> 1;
  int dhalf = blockIdx.x & 1;
  int v0 = chunk << 7;
  int t = threadIdx.x;
#pragma unroll
  for (int k = 0; k < 16; ++k) {            // stage W[b][v0..v0+128) -> wsh[v][b]
    int idx = (k << 8) + t;
    int b = idx >> 7, v = idx & 127;
    wsh[v][b] = W[(size_t)b * VV + v0 + v];
  }
  __syncthreads();
  float acc[32];
#pragma unroll
  for (int b = 0; b < 32; ++b) acc[b] = 0.f;
  const float* tp = table + (size_t)v0 * DD + (dhalf << 8) + t;
  for (int vb = 0; vb < 128; vb += 8) {
    float r[8];
#pragma unroll
    for (int j = 0; j < 8; ++j) r[j] = tp[(size_t)(vb + j) * DD];   // 8 loads in flight
#pragma unroll
    for (int j = 0; j < 8; ++j)
#pragma unroll
      for (int b = 0; b < 32; ++b) acc[b] += wsh[vb + j][b] * r[j];
  }
  float* pp = part + (size_t)chunk * (32 * DD) + (dhalf << 8) + t;
#pragma unroll
  for (int b = 0; b < 32; ++b) pp[(size_t)b * DD] = acc[b];
}

// ---- uout[b][d] = (prev?prev:0) + sum_{c<250} part[c][b][d]
__global__ void reduceV_kernel(const float* __restrict__ part,
                               const float* __restrict__ prev,
                               float* __restrict__ uout) {
  int i = blockIdx.x * 256 + threadIdx.x;   // 64 blocks -> B*D
  float acc = 0.f;
  for (int c = 0; c < NCHUNK; ++c) acc += part[(size_t)c * 16384 + i];
  uout[i] = (prev ? prev[i] : 0.f) + acc;
}

// ---- decoder hop0 variant: o = sum part; uk = hid + o; hc = [hid | o]
__global__ void reduceV2_kernel(const float* __restrict__ part,
                                const float* __restrict__ hid,
                                float* __restrict__ uk, float* __restrict__ hc) {
  int i = blockIdx.x * 256 + threadIdx.x;
  int b = i >> 9, d = i & 511;
  float o = 0.f;
  for (int c = 0; c < NCHUNK; ++c) o += part[(size_t)c * 16384 + i];
  float hv = hid[i];
  uk[i] = hv + o;
  hc[b * 1024 + d] = hv;
  hc[b * 1024 + 512 + d] = o;
}

// ---- fused gather + dot: s[p] = (sum_t table[story[p,t]]) . u[b]. One wave per p.
__global__ __launch_bounds__(256) void pooldot_kernel(const float* __restrict__ table,
                                                      const int* __restrict__ story,
                                                      const float* __restrict__ u,
                                                      float* __restrict__ s) {
  int wave = (blockIdx.x << 2) + (threadIdx.x >> 6);
  int lane = threadIdx.x & 63;
  int b = wave >> 9;
  const int* st = story + wave * TT;
  size_t r0 = (size_t)st[0] * DD, r1 = (size_t)st[1] * DD;
  size_t r2 = (size_t)st[2] * DD, r3 = (size_t)st[3] * DD;
  const float4* t4 = (const float4*)table;
  const float4* ur = (const float4*)(u + (size_t)b * DD);
  float acc = 0.f;
#pragma unroll
  for (int h = 0; h < 2; ++h) {
    int c = (h << 6) + lane;
    float4 a = t4[(r0 >> 2) + c];
    float4 bb = t4[(r1 >> 2) + c];
    float4 cc = t4[(r2 >> 2) + c];
    float4 d = t4[(r3 >> 2) + c];
    float4 q = ur[c];
    acc += (a.x + bb.x + cc.x + d.x) * q.x;
    acc += (a.y + bb.y + cc.y + d.y) * q.y;
    acc += (a.z + bb.z + cc.z + d.z) * q.z;
    acc += (a.w + bb.w + cc.w + d.w) * q.w;
  }
#pragma unroll
  for (int off = 32; off > 0; off >>= 1) acc += __shfl_xor(acc, off);
  if (lane == 0) s[wave] = acc;
}

// ---- out[b][j] = bias[j] + W[j] . (vin ? vin[b] : table[q[b]]). One wave per (b,j).
__global__ __launch_bounds__(256) void matvec_kernel(const float* __restrict__ W,
                                                     const float* __restrict__ bias,
                                                     const float* __restrict__ vin,
                                                     const int* __restrict__ q,
                                                     const float* __restrict__ table,
                                                     float* __restrict__ out) {
  int idx = (blockIdx.x << 2) + (threadIdx.x >> 6);  // b*1536 + j
  int lane = threadIdx.x & 63;
  int b = idx / 1536;
  int j = idx - b * 1536;
  const float* xb = vin ? (vin + (size_t)b * DD) : (table + (size_t)q[b] * DD);
  const float4* Wr = (const float4*)(W + (size_t)j * DD);
  const float4* xr = (const float4*)xb;
  float acc = 0.f;
#pragma unroll
  for (int h = 0; h < 2; ++h) {
    int c = (h << 6) + lane;
    float4 a = Wr[c];
    float4 qv = xr[c];
    acc += a.x * qv.x + a.y * qv.y + a.z * qv.z + a.w * qv.w;
  }
#pragma unroll
  for (int off = 32; off > 0; off >>= 1) acc += __shfl_xor(acc, off);
  if (lane == 0) out[idx] = acc + bias[j];
}

// ---- GRU gates: hidden = (1-z)*n + z*u
__global__ void gate_kernel(const float* __restrict__ gi, const float* __restrict__ gh,
                            const float* __restrict__ u, float* __restrict__ hidden,
                            float* __restrict__ out_h) {
  int i = blockIdx.x * 256 + threadIdx.x;  // B*D
  int b = i >> 9, d = i & 511;
  const float* gib = gi + b * 1536;
  const float* ghb = gh + b * 1536;
  float i_r = gib[d], i_z = gib[d + 512], i_n = gib[d + 1024];
  float h_r = ghb[d], h_z = ghb[d + 512], h_n = ghb[d + 1024];
  float r = 1.f / (1.f + expf(-(i_r + h_r)));
  float z = 1.f / (1.f + expf(-(i_z + h_z)));
  float n = tanhf(i_n + r * h_n);
  float h = (1.f - z) * n + z * u[i];
  hidden[i] = h;
  out_h[i] = h;
}

// ---- p_vocab partials, split-K x2: partc[kh][b][v]
__global__ __launch_bounds__(256) void pvocab_kernel(const float* __restrict__ Hcat,
                                                     const float* __restrict__ W1,
                                                     float* __restrict__ partc) {
  __shared__ float As[32][36];
  __shared__ float Bs[32][68];
  int t = threadIdx.x;
  int vt = blockIdx.x >> 1;
  int kh = blockIdx.x & 1;
  int v0 = vt * 64;
  int kbase = kh << 9;            // 0 or 512
  int tb = t >> 5;
  int tv = t & 31;
  int br = t >> 2;
  int bk = (t & 3) << 3;
  const float* Wp = W1 + (size_t)(v0 + br) * 1024 + kbase + bk;
  int ab = t >> 3;
  int ak = (t & 7) << 2;
  const float* Ap = Hcat + (size_t)ab * 1024 + kbase + ak;

  float acc[4][2] = {{0.f, 0.f}, {0.f, 0.f}, {0.f, 0.f}, {0.f, 0.f}};

  float4 aReg = *(const float4*)(Ap);
  float4 wReg0 = *(const float4*)(Wp);
  float4 wReg1 = *(const float4*)(Wp + 4);

  for (int k0 = 0; k0 < 512; k0 += 32) {
    As[ak + 0][ab] = aReg.x; As[ak + 1][ab] = aReg.y;
    As[ak + 2][ab] = aReg.z; As[ak + 3][ab] = aReg.w;
    Bs[bk + 0][br] = wReg0.x; Bs[bk + 1][br] = wReg0.y;
    Bs[bk + 2][br] = wReg0.z; Bs[bk + 3][br] = wReg0.w;
    Bs[bk + 4][br] = wReg1.x; Bs[bk + 5][br] = wReg1.y;
    Bs[bk + 6][br] = wReg1.z; Bs[bk + 7][br] = wReg1.w;
    __syncthreads();
    if (k0 + 32 < 512) {
      aReg = *(const float4*)(Ap + k0 + 32);
      wReg0 = *(const float4*)(Wp + k0 + 32);
      wReg1 = *(const float4*)(Wp + k0 + 36);
    }
#pragma unroll
    for (int k = 0; k < 32; ++k) {
      float2 bv = *(const float2*)&Bs[k][tv * 2];
      float4 av = *(const float4*)&As[k][tb * 4];
      acc[0][0] += av.x * bv.x; acc[0][1] += av.x * bv.y;
      acc[1][0] += av.y * bv.x; acc[1][1] += av.y * bv.y;
      acc[2][0] += av.z * bv.x; acc[2][1] += av.z * bv.y;
      acc[3][0] += av.w * bv.x; acc[3][1] += av.w * bv.y;
    }
    __syncthreads();
  }
  int v = v0 + tv * 2;
  float* base = partc + (size_t)kh * BV;
#pragma unroll
  for (int i = 0; i < 4; ++i) {
    float2 r;
    r.x = acc[i][0];
    r.y = acc[i][1];
    *(float2*)(base + (size_t)(tb * 4 + i) * VV + v) = r;
  }
}

// ---- out[b][v] = partc[0][b][v] + partc[1][b][v] + W1b[v].  grid (125, 32).
__global__ void pvreduce_kernel(const float* __restrict__ partc,
                                const float* __restrict__ W1b,
                                float* __restrict__ out) {
  int v = blockIdx.x * 256 + threadIdx.x;   // 125*256 = 32000
  int b = blockIdx.y;
  size_t o = (size_t)b * VV + v;
  out[o] = partc[o] + partc[BV + o] + W1b[v];
}

extern "C" void kernel_launch(void* const* d_in, const int* in_sizes, int n_in,
                              void* d_out, int out_size, void* d_ws, size_t ws_size,
                              hipStream_t stream) {
  const int* story = (const int*)d_in[0];
  const int* q = (const int*)d_in[1];
  const float* C_enc = (const float*)d_in[2];
  const float* C_dec = (const float*)d_in[3];
  const float* W_ih = (const float*)d_in[4];
  const float* W_hh = (const float*)d_in[5];
  const float* b_ih = (const float*)d_in[6];
  const float* b_hh = (const float*)d_in[7];
  const float* W1 = (const float*)d_in[8];
  const float* W1b = (const float*)d_in[9];
  float* out = (float*)d_out;

  const size_t VD = (size_t)VV * DD;
  const float* C1 = C_enc + 1 * VD;
  const float* C2 = C_enc + 2 * VD;
  const float* C3 = C_enc + 3 * VD;
  const float* D0 = C_dec + 0 * VD;
  const float* D1 = C_dec + 1 * VD;
  const float* D2 = C_dec + 2 * VD;

  float* accW = (float*)d_ws;                      // [B*V]
  float* part = accW + BV;                         // [250*32*512]
  float* partc = part + (size_t)NCHUNK * 32 * DD;  // [2*B*V]
  float* u = partc + 2 * BV;                       // [B*D]
  float* s = u + BB * DD;                          // [B*M]
  float* gi = s + BB * MM;                         // [B*3D]
  float* gh = gi + BB * 3 * DD;                    // [B*3D]
  float* hid = gh + BB * 3 * DD;                   // [B*D]
  float* uk = hid + BB * DD;                       // [B*D]
  float* hc = uk + BB * DD;                        // [B*2D]

  float* p_ptr_out = out;
  float* p_vocab_out = out + BB * MM;
  float* hid_out = out + BB * MM + (size_t)BB * VV;

  dim3 blk(256);
  const dim3 wsGrid(4, BB);            // wscatter: (quarter, b)
  const int wvGrid = NCHUNK * 2;       // 500 blocks (v-chunk x d-half)
  const int pdGrid = BB * MM / 4;      // 4096 blocks x 4 waves
  const int mvGrid = BB * 3 * DD / 4;  // 3072 blocks
  const int ewGrid = BB * DD / 256;    // 64

  // ---------------- encoder (u0 = 0 => hop0 softmax uniform; C_enc[0] unused)
  wscatter_kernel<<<wsGrid, blk, 0, stream>>>(nullptr, story, accW);   // uniform
  wsumV_kernel<<<wvGrid, blk, 0, stream>>>(C1, accW, part);
  reduceV_kernel<<<ewGrid, blk, 0, stream>>>(part, nullptr, u);        // u1
  pooldot_kernel<<<pdGrid, blk, 0, stream>>>(C1, story, u, s);         // s1 (C1 L3-hot)
  wscatter_kernel<<<wsGrid, blk, 0, stream>>>(s, story, accW);
  wsumV_kernel<<<wvGrid, blk, 0, stream>>>(C2, accW, part);
  reduceV_kernel<<<ewGrid, blk, 0, stream>>>(part, u, u);              // u2
  pooldot_kernel<<<pdGrid, blk, 0, stream>>>(C2, story, u, s);         // s2 (C2 L3-hot)
  wscatter_kernel<<<wsGrid, blk, 0, stream>>>(s, story, accW);
  wsumV_kernel<<<wvGrid, blk, 0, stream>>>(C3, accW, part);
  reduceV_kernel<<<ewGrid, blk, 0, stream>>>(part, u, u);              // u3 = enc_hidden

  // ---------------- GRU step (embed folded into matvec_gi)
  matvec_kernel<<<mvGrid, blk, 0, stream>>>(W_ih, b_ih, nullptr, q, C_dec, gi);
  matvec_kernel<<<mvGrid, blk, 0, stream>>>(W_hh, b_hh, u, nullptr, nullptr, gh);
  gate_kernel<<<ewGrid, blk, 0, stream>>>(gi, gh, u, hid, hid_out);

  // ---------------- pointer decoder (C_dec[3] pooled is dead code)
  pooldot_kernel<<<pdGrid, blk, 0, stream>>>(D0, story, hid, s);       // hop0 logits
  wscatter_kernel<<<wsGrid, blk, 0, stream>>>(s, story, accW);
  wsumV_kernel<<<wvGrid, blk, 0, stream>>>(D1, accW, part);
  reduceV2_kernel<<<ewGrid, blk, 0, stream>>>(part, hid, uk, hc);      // o0, uk1, hcat
  pooldot_kernel<<<pdGrid, blk, 0, stream>>>(D1, story, uk, s);        // hop1 logits (D1 hot)
  wscatter_kernel<<<wsGrid, blk, 0, stream>>>(s, story, accW);
  wsumV_kernel<<<wvGrid, blk, 0, stream>>>(D2, accW, part);
  reduceV_kernel<<<ewGrid, blk, 0, stream>>>(part, uk, uk);            // uk2
  pooldot_kernel<<<pdGrid, blk, 0, stream>>>(D2, story, uk, p_ptr_out); // p_ptr (D2 hot)

  // ---------------- vocab projection (split-K x2 + reduce)
  pvocab_kernel<<<VV / 64 * 2, blk, 0, stream>>>(hc, W1, partc);
  pvreduce_kernel<<<dim3(125, 32), blk, 0, stream>>>(partc, W1b, p_vocab_out);
}

// Round 11
// 268.360 us; speedup vs baseline: 1.9821x; 1.7527x over previous
//
#include <hip/hip_runtime.h>
#include <math.h>

#define DD 512
#define MM 512
#define BB 32
#define TT 4
#define VV 32000
#define BV ((size_t)BB * VV)

// ---- fused gather + softmax-weighted partial sum + optional P materialization.
// block = b*32 + c (c = 16-m chunk). Gathers 64 story rows, pools per-m (4 rows),
// optionally writes pooled row to P[b][m][:], accumulates w[m]*pooled into partial.
// w = softmax(s[b]) computed redundantly per block; s==null -> 1/M.
__global__ __launch_bounds__(256) void poolwsumP_kernel(const float* __restrict__ table,
                                                        const int* __restrict__ story,
                                                        const float* __restrict__ s,
                                                        float* __restrict__ P,
                                                        float* __restrict__ partial) {
  __shared__ float wrow[16];
  __shared__ int rows[64];
  __shared__ float red[16];
  __shared__ float4 comb[128];
  int b = blockIdx.x >> 5;
  int c = blockIdx.x & 31;
  int t = threadIdx.x;
  if (s) {
    float v0 = s[b * MM + t], v1 = s[b * MM + t + 256];
    float mx = fmaxf(v0, v1);
#pragma unroll
    for (int off = 32; off > 0; off >>= 1) mx = fmaxf(mx, __shfl_xor(mx, off));
    if ((t & 63) == 0) red[t >> 6] = mx;
    __syncthreads();
    mx = fmaxf(fmaxf(red[0], red[1]), fmaxf(red[2], red[3]));
    float e0 = expf(v0 - mx), e1 = expf(v1 - mx);
    float sm = e0 + e1;
#pragma unroll
    for (int off = 32; off > 0; off >>= 1) sm += __shfl_xor(sm, off);
    if ((t & 63) == 0) red[8 + (t >> 6)] = sm;
    __syncthreads();
    sm = red[8] + red[9] + red[10] + red[11];
    float inv = 1.0f / sm;
    if (t < 16) wrow[t] = expf(s[b * MM + (c << 4) + t] - mx) * inv;
  } else {
    if (t < 16) wrow[t] = 1.0f / MM;
  }
  if (t < 64) rows[t] = story[((b << 9) + (c << 4)) * TT + t];
  __syncthreads();
  int h = t >> 7;             // half: 0 or 1
  int col = t & 127;          // float4 column
  float4 acc = make_float4(0.f, 0.f, 0.f, 0.f);
#pragma unroll
  for (int i = 0; i < 8; ++i) {
    int lm = (i << 1) + h;    // local m, half-interleaved
    const float4* r0 = (const float4*)(table + (size_t)rows[lm * 4 + 0] * DD);
    const float4* r1 = (const float4*)(table + (size_t)rows[lm * 4 + 1] * DD);
    const float4* r2 = (const float4*)(table + (size_t)rows[lm * 4 + 2] * DD);
    const float4* r3 = (const float4*)(table + (size_t)rows[lm * 4 + 3] * DD);
    float4 a = r0[col], bb = r1[col], cc = r2[col], d = r3[col];
    float4 pooled;
    pooled.x = a.x + bb.x + cc.x + d.x;
    pooled.y = a.y + bb.y + cc.y + d.y;
    pooled.z = a.z + bb.z + cc.z + d.z;
    pooled.w = a.w + bb.w + cc.w + d.w;
    if (P) ((float4*)(P + ((size_t)(b << 9) + (c << 4) + lm) * DD))[col] = pooled;
    float wm = wrow[lm];
    acc.x += wm * pooled.x; acc.y += wm * pooled.y;
    acc.z += wm * pooled.z; acc.w += wm * pooled.w;
  }
  if (h) comb[col] = acc;
  __syncthreads();
  if (!h) {
    float4 o = comb[col];
    acc.x += o.x; acc.y += o.y; acc.z += o.z; acc.w += o.w;
    ((float4*)(partial + (size_t)blockIdx.x * DD))[col] = acc;
  }
}

// ---- stream dot over materialized P: s[b][m] = P[b][m][:] . u[b][:].
// grid 1024 (b*32 + 16-m chunk), 4 waves; wave handles 4 m's, u cached in regs.
__global__ __launch_bounds__(256) void Pdot_kernel(const float* __restrict__ P,
                                                   const float* __restrict__ u,
                                                   float* __restrict__ s) {
  int b = blockIdx.x >> 5;
  int c = blockIdx.x & 31;
  int w = threadIdx.x >> 6;
  int lane = threadIdx.x & 63;
  const float4* ur = (const float4*)(u + (size_t)b * DD);
  float4 u0 = ur[lane], u1 = ur[lane + 64];
  const float4* Pb = (const float4*)(P + ((size_t)(b << 9) + (c << 4)) * DD);
#pragma unroll
  for (int j = 0; j < 4; ++j) {
    int m = (w << 2) + j;     // local m 0..15
    const float4* pr = Pb + (size_t)m * 128;
    float4 a = pr[lane], bb = pr[lane + 64];
    float acc = a.x * u0.x + a.y * u0.y + a.z * u0.z + a.w * u0.w
              + bb.x * u1.x + bb.y * u1.y + bb.z * u1.z + bb.w * u1.w;
#pragma unroll
    for (int off = 32; off > 0; off >>= 1) acc += __shfl_xor(acc, off);
    if (lane == 0) s[(b << 9) + (c << 4) + m] = acc;
  }
}

// ---- stage B: uout[b][d] = (prev ? prev[b][d] : 0) + sum_{c<32} partial[b*32+c][d]
__global__ void wsumB_kernel(const float* __restrict__ partial,
                             const float* __restrict__ prev,
                             float* __restrict__ uout) {
  int i = blockIdx.x * 256 + threadIdx.x;   // 64 blocks -> B*D
  int b = i >> 9, d = i & 511;
  float acc = prev ? prev[i] : 0.f;
  const float* pp = partial + (size_t)b * 32 * DD + d;
#pragma unroll
  for (int c = 0; c < 32; ++c) acc += pp[c * DD];
  uout[i] = acc;
}

// ---- stage B, decoder hop0: o0 = sum partials; uk = hid + o0; hc = [hid | o0]
__global__ void wsumB2_kernel(const float* __restrict__ partial,
                              const float* __restrict__ hid,
                              float* __restrict__ uk, float* __restrict__ hc) {
  int i = blockIdx.x * 256 + threadIdx.x;
  int b = i >> 9, d = i & 511;
  float ov = 0.f;
  const float* pp = partial + (size_t)b * 32 * DD + d;
#pragma unroll
  for (int c = 0; c < 32; ++c) ov += pp[c * DD];
  float hv = hid[i];
  uk[i] = hv + ov;
  hc[b * 1024 + d] = hv;
  hc[b * 1024 + 512 + d] = ov;
}

// ---- fused gather + dot (for dot-only table D0): one wave per (b,m).
__global__ __launch_bounds__(256) void pooldot_kernel(const float* __restrict__ table,
                                                      const int* __restrict__ story,
                                                      const float* __restrict__ u,
                                                      float* __restrict__ s) {
  int wave = (blockIdx.x << 2) + (threadIdx.x >> 6);
  int lane = threadIdx.x & 63;
  int b = wave >> 9;
  const int* st = story + wave * TT;
  size_t r0 = (size_t)st[0] * DD, r1 = (size_t)st[1] * DD;
  size_t r2 = (size_t)st[2] * DD, r3 = (size_t)st[3] * DD;
  const float4* t4 = (const float4*)table;
  const float4* ur = (const float4*)(u + (size_t)b * DD);
  float acc = 0.f;
#pragma unroll
  for (int h = 0; h < 2; ++h) {
    int c = (h << 6) + lane;
    float4 a = t4[(r0 >> 2) + c];
    float4 bb = t4[(r1 >> 2) + c];
    float4 cc = t4[(r2 >> 2) + c];
    float4 d = t4[(r3 >> 2) + c];
    float4 q = ur[c];
    acc += (a.x + bb.x + cc.x + d.x) * q.x;
    acc += (a.y + bb.y + cc.y + d.y) * q.y;
    acc += (a.z + bb.z + cc.z + d.z) * q.z;
    acc += (a.w + bb.w + cc.w + d.w) * q.w;
  }
#pragma unroll
  for (int off = 32; off > 0; off >>= 1) acc += __shfl_xor(acc, off);
  if (lane == 0) s[wave] = acc;
}

// ---- out[b][j] = bias[j] + W[j] . (vin ? vin[b] : table[q[b]]). One wave per (b,j).
__global__ __launch_bounds__(256) void matvec_kernel(const float* __restrict__ W,
                                                     const float* __restrict__ bias,
                                                     const float* __restrict__ vin,
                                                     const int* __restrict__ q,
                                                     const float* __restrict__ table,
                                                     float* __restrict__ out) {
  int idx = (blockIdx.x << 2) + (threadIdx.x >> 6);  // b*1536 + j
  int lane = threadIdx.x & 63;
  int b = idx / 1536;
  int j = idx - b * 1536;
  const float* xb = vin ? (vin + (size_t)b * DD) : (table + (size_t)q[b] * DD);
  const float4* Wr = (const float4*)(W + (size_t)j * DD);
  const float4* xr = (const float4*)xb;
  float acc = 0.f;
#pragma unroll
  for (int h = 0; h < 2; ++h) {
    int c = (h << 6) + lane;
    float4 a = Wr[c];
    float4 qv = xr[c];
    acc += a.x * qv.x + a.y * qv.y + a.z * qv.z + a.w * qv.w;
  }
#pragma unroll
  for (int off = 32; off > 0; off >>= 1) acc += __shfl_xor(acc, off);
  if (lane == 0) out[idx] = acc + bias[j];
}

// ---- GRU gates: hidden = (1-z)*n + z*u
__global__ void gate_kernel(const float* __restrict__ gi, const float* __restrict__ gh,
                            const float* __restrict__ u, float* __restrict__ hidden,
                            float* __restrict__ out_h) {
  int i = blockIdx.x * 256 + threadIdx.x;  // B*D
  int b = i >> 9, d = i & 511;
  const float* gib = gi + b * 1536;
  const float* ghb = gh + b * 1536;
  float i_r = gib[d], i_z = gib[d + 512], i_n = gib[d + 1024];
  float h_r = ghb[d], h_z = ghb[d + 512], h_n = ghb[d + 1024];
  float r = 1.f / (1.f + expf(-(i_r + h_r)));
  float z = 1.f / (1.f + expf(-(i_z + h_z)));
  float n = tanhf(i_n + r * h_n);
  float h = (1.f - z) * n + z * u[i];
  hidden[i] = h;
  out_h[i] = h;
}

// ---- p_vocab partials, split-K x2: partc[kh][b][v]
__global__ __launch_bounds__(256) void pvocab_kernel(const float* __restrict__ Hcat,
                                                     const float* __restrict__ W1,
                                                     float* __restrict__ partc) {
  __shared__ float As[32][36];
  __shared__ float Bs[32][68];
  int t = threadIdx.x;
  int vt = blockIdx.x >> 1;
  int kh = blockIdx.x & 1;
  int v0 = vt * 64;
  int kbase = kh << 9;            // 0 or 512
  int tb = t >> 5;
  int tv = t & 31;
  int br = t >> 2;
  int bk = (t & 3) << 3;
  const float* Wp = W1 + (size_t)(v0 + br) * 1024 + kbase + bk;
  int ab = t >> 3;
  int ak = (t & 7) << 2;
  const float* Ap = Hcat + (size_t)ab * 1024 + kbase + ak;

  float acc[4][2] = {{0.f, 0.f}, {0.f, 0.f}, {0.f, 0.f}, {0.f, 0.f}};

  float4 aReg = *(const float4*)(Ap);
  float4 wReg0 = *(const float4*)(Wp);
  float4 wReg1 = *(const float4*)(Wp + 4);

  for (int k0 = 0; k0 < 512; k0 += 32) {
    As[ak + 0][ab] = aReg.x; As[ak + 1][ab] = aReg.y;
    As[ak + 2][ab] = aReg.z; As[ak + 3][ab] = aReg.w;
    Bs[bk + 0][br] = wReg0.x; Bs[bk + 1][br] = wReg0.y;
    Bs[bk + 2][br] = wReg0.z; Bs[bk + 3][br] = wReg0.w;
    Bs[bk + 4][br] = wReg1.x; Bs[bk + 5][br] = wReg1.y;
    Bs[bk + 6][br] = wReg1.z; Bs[bk + 7][br] = wReg1.w;
    __syncthreads();
    if (k0 + 32 < 512) {
      aReg = *(const float4*)(Ap + k0 + 32);
      wReg0 = *(const float4*)(Wp + k0 + 32);
      wReg1 = *(const float4*)(Wp + k0 + 36);
    }
#pragma unroll
    for (int k = 0; k < 32; ++k) {
      float2 bv = *(const float2*)&Bs[k][tv * 2];
      float4 av = *(const float4*)&As[k][tb * 4];
      acc[0][0] += av.x * bv.x; acc[0][1] += av.x * bv.y;
      acc[1][0] += av.y * bv.x; acc[1][1] += av.y * bv.y;
      acc[2][0] += av.z * bv.x; acc[2][1] += av.z * bv.y;
      acc[3][0] += av.w * bv.x; acc[3][1] += av.w * bv.y;
    }
    __syncthreads();
  }
  int v = v0 + tv * 2;
  float* base = partc + (size_t)kh * BV;
#pragma unroll
  for (int i = 0; i < 4; ++i) {
    float2 r;
    r.x = acc[i][0];
    r.y = acc[i][1];
    *(float2*)(base + (size_t)(tb * 4 + i) * VV + v) = r;
  }
}

// ---- out[b][v] = partc[0][b][v] + partc[1][b][v] + W1b[v].  grid (125, 32).
__global__ void pvreduce_kernel(const float* __restrict__ partc,
                                const float* __restrict__ W1b,
                                float* __restrict__ out) {
  int v = blockIdx.x * 256 + threadIdx.x;   // 125*256 = 32000
  int b = blockIdx.y;
  size_t o = (size_t)b * VV + v;
  out[o] = partc[o] + partc[BV + o] + W1b[v];
}

extern "C" void kernel_launch(void* const* d_in, const int* in_sizes, int n_in,
                              void* d_out, int out_size, void* d_ws, size_t ws_size,
                              hipStream_t stream) {
  const int* story = (const int*)d_in[0];
  const int* q = (const int*)d_in[1];
  const float* C_enc = (const float*)d_in[2];
  const float* C_dec = (const float*)d_in[3];
  const float* W_ih = (const float*)d_in[4];
  const float* W_hh = (const float*)d_in[5];
  const float* b_ih = (const float*)d_in[6];
  const float* b_hh = (const float*)d_in[7];
  const float* W1 = (const float*)d_in[8];
  const float* W1b = (const float*)d_in[9];
  float* out = (float*)d_out;

  const size_t VD = (size_t)VV * DD;
  const float* C1 = C_enc + 1 * VD;
  const float* C2 = C_enc + 2 * VD;
  const float* C3 = C_enc + 3 * VD;
  const float* D0 = C_dec + 0 * VD;
  const float* D1 = C_dec + 1 * VD;
  const float* D2 = C_dec + 2 * VD;

  float* P = (float*)d_ws;                         // [B*M*D] materialized pool
  float* part = P + (size_t)BB * MM * DD;          // [B*32*D]
  float* partc = part + (size_t)BB * 32 * DD;      // [2*B*V]
  float* u = partc + 2 * BV;                       // [B*D]
  float* s = u + BB * DD;                          // [B*M]
  float* gi = s + BB * MM;                         // [B*3D]
  float* gh = gi + BB * 3 * DD;                    // [B*3D]
  float* hid = gh + BB * 3 * DD;                   // [B*D]
  float* uk = hid + BB * DD;                       // [B*D]
  float* hc = uk + BB * DD;                        // [B*2D]

  float* p_ptr_out = out;
  float* p_vocab_out = out + BB * MM;
  float* hid_out = out + BB * MM + (size_t)BB * VV;

  dim3 blk(256);
  const int pwGrid = BB * 32;          // 1024 blocks
  const int pdGrid = BB * MM / 4;      // 4096 blocks (pooldot)
  const int PdGrid = BB * 32;          // 1024 blocks (Pdot)
  const int mvGrid = BB * 3 * DD / 4;  // 3072 blocks
  const int ewGrid = BB * DD / 256;    // 64

  // ---------------- encoder (u0 = 0 => hop0 softmax uniform; C_enc[0] unused)
  poolwsumP_kernel<<<pwGrid, blk, 0, stream>>>(C1, story, nullptr, P, part);
  wsumB_kernel<<<ewGrid, blk, 0, stream>>>(part, nullptr, u);      // u1 = mean pool
  Pdot_kernel<<<PdGrid, blk, 0, stream>>>(P, u, s);                // s1 (stream over P)
  poolwsumP_kernel<<<pwGrid, blk, 0, stream>>>(C2, story, s, P, part);
  wsumB_kernel<<<ewGrid, blk, 0, stream>>>(part, u, u);            // u2
  Pdot_kernel<<<PdGrid, blk, 0, stream>>>(P, u, s);                // s2
  poolwsumP_kernel<<<pwGrid, blk, 0, stream>>>(C3, story, s, nullptr, part);  // no P
  wsumB_kernel<<<ewGrid, blk, 0, stream>>>(part, u, u);            // u3 = enc_hidden

  // ---------------- GRU step (embed folded into matvec_gi)
  matvec_kernel<<<mvGrid, blk, 0, stream>>>(W_ih, b_ih, nullptr, q, C_dec, gi);
  matvec_kernel<<<mvGrid, blk, 0, stream>>>(W_hh, b_hh, u, nullptr, nullptr, gh);
  gate_kernel<<<ewGrid, blk, 0, stream>>>(gi, gh, u, hid, hid_out);

  // ---------------- pointer decoder (C_dec[3] pooled is dead code)
  pooldot_kernel<<<pdGrid, blk, 0, stream>>>(D0, story, hid, s);   // hop0 logits (gather)
  poolwsumP_kernel<<<pwGrid, blk, 0, stream>>>(D1, story, s, P, part);
  wsumB2_kernel<<<ewGrid, blk, 0, stream>>>(part, hid, uk, hc);    // o0, uk1, hcat
  Pdot_kernel<<<PdGrid, blk, 0, stream>>>(P, uk, s);               // hop1 logits
  poolwsumP_kernel<<<pwGrid, blk, 0, stream>>>(D2, story, s, P, part);
  wsumB_kernel<<<ewGrid, blk, 0, stream>>>(part, uk, uk);          // uk2
  Pdot_kernel<<<PdGrid, blk, 0, stream>>>(P, uk, p_ptr_out);       // p_ptr

  // ---------------- vocab projection (split-K x2 + reduce)
  pvocab_kernel<<<VV / 64 * 2, blk, 0, stream>>>(hc, W1, partc);
  pvreduce_kernel<<<dim3(125, 32), blk, 0, stream>>>(partc, W1b, p_vocab_out);
}

// Round 12
// 266.298 us; speedup vs baseline: 1.9974x; 1.0077x over previous
//
#include <hip/hip_runtime.h>
#include <math.h>

#define DD 512
#define MM 512
#define BB 32
#define TT 4
#define VV 32000
#define BV ((size_t)BB * VV)

// ---- fused gather + softmax-weighted partial sum + optional P materialization.
// block = b*32 + c (c = 16-m chunk). Gathers 64 story rows, pools per-m (4 rows),
// optionally writes pooled row to P[b][m][:], accumulates w[m]*pooled into partial.
// w = softmax(s[b]) computed redundantly per block; s==null -> 1/M.
__global__ __launch_bounds__(256) void poolwsumP_kernel(const float* __restrict__ table,
                                                        const int* __restrict__ story,
                                                        const float* __restrict__ s,
                                                        float* __restrict__ P,
                                                        float* __restrict__ partial) {
  __shared__ float wrow[16];
  __shared__ int rows[64];
  __shared__ float red[16];
  __shared__ float4 comb[128];
  int b = blockIdx.x >> 5;
  int c = blockIdx.x & 31;
  int t = threadIdx.x;
  if (s) {
    float v0 = s[b * MM + t], v1 = s[b * MM + t + 256];
    float mx = fmaxf(v0, v1);
#pragma unroll
    for (int off = 32; off > 0; off >>= 1) mx = fmaxf(mx, __shfl_xor(mx, off));
    if ((t & 63) == 0) red[t >> 6] = mx;
    __syncthreads();
    mx = fmaxf(fmaxf(red[0], red[1]), fmaxf(red[2], red[3]));
    float e0 = expf(v0 - mx), e1 = expf(v1 - mx);
    float sm = e0 + e1;
#pragma unroll
    for (int off = 32; off > 0; off >>= 1) sm += __shfl_xor(sm, off);
    if ((t & 63) == 0) red[8 + (t >> 6)] = sm;
    __syncthreads();
    sm = red[8] + red[9] + red[10] + red[11];
    float inv = 1.0f / sm;
    if (t < 16) wrow[t] = expf(s[b * MM + (c << 4) + t] - mx) * inv;
  } else {
    if (t < 16) wrow[t] = 1.0f / MM;
  }
  if (t < 64) rows[t] = story[((b << 9) + (c << 4)) * TT + t];
  __syncthreads();
  int h = t >> 7;             // half: 0 or 1
  int col = t & 127;          // float4 column
  float4 acc = make_float4(0.f, 0.f, 0.f, 0.f);
#pragma unroll
  for (int i = 0; i < 8; ++i) {
    int lm = (i << 1) + h;    // local m, half-interleaved
    const float4* r0 = (const float4*)(table + (size_t)rows[lm * 4 + 0] * DD);
    const float4* r1 = (const float4*)(table + (size_t)rows[lm * 4 + 1] * DD);
    const float4* r2 = (const float4*)(table + (size_t)rows[lm * 4 + 2] * DD);
    const float4* r3 = (const float4*)(table + (size_t)rows[lm * 4 + 3] * DD);
    float4 a = r0[col], bb = r1[col], cc = r2[col], d = r3[col];
    float4 pooled;
    pooled.x = a.x + bb.x + cc.x + d.x;
    pooled.y = a.y + bb.y + cc.y + d.y;
    pooled.z = a.z + bb.z + cc.z + d.z;
    pooled.w = a.w + bb.w + cc.w + d.w;
    if (P) ((float4*)(P + ((size_t)(b << 9) + (c << 4) + lm) * DD))[col] = pooled;
    float wm = wrow[lm];
    acc.x += wm * pooled.x; acc.y += wm * pooled.y;
    acc.z += wm * pooled.z; acc.w += wm * pooled.w;
  }
  if (h) comb[col] = acc;
  __syncthreads();
  if (!h) {
    float4 o = comb[col];
    acc.x += o.x; acc.y += o.y; acc.z += o.z; acc.w += o.w;
    ((float4*)(partial + (size_t)blockIdx.x * DD))[col] = acc;
  }
}

// ---- stream dot over materialized P: s[b][m] = P[b][m][:] . u[b][:].
__global__ __launch_bounds__(256) void Pdot_kernel(const float* __restrict__ P,
                                                   const float* __restrict__ u,
                                                   float* __restrict__ s) {
  int b = blockIdx.x >> 5;
  int c = blockIdx.x & 31;
  int w = threadIdx.x >> 6;
  int lane = threadIdx.x & 63;
  const float4* ur = (const float4*)(u + (size_t)b * DD);
  float4 u0 = ur[lane], u1 = ur[lane + 64];
  const float4* Pb = (const float4*)(P + ((size_t)(b << 9) + (c << 4)) * DD);
#pragma unroll
  for (int j = 0; j < 4; ++j) {
    int m = (w << 2) + j;     // local m 0..15
    const float4* pr = Pb + (size_t)m * 128;
    float4 a = pr[lane], bb = pr[lane + 64];
    float acc = a.x * u0.x + a.y * u0.y + a.z * u0.z + a.w * u0.w
              + bb.x * u1.x + bb.y * u1.y + bb.z * u1.z + bb.w * u1.w;
#pragma unroll
    for (int off = 32; off > 0; off >>= 1) acc += __shfl_xor(acc, off);
    if (lane == 0) s[(b << 9) + (c << 4) + m] = acc;
  }
}

// ---- stage B: uout[b][d] = (prev ? prev[b][d] : 0) + sum_{c<32} partial[b*32+c][d]
__global__ void wsumB_kernel(const float* __restrict__ partial,
                             const float* __restrict__ prev,
                             float* __restrict__ uout) {
  int i = blockIdx.x * 256 + threadIdx.x;   // 64 blocks -> B*D
  int b = i >> 9, d = i & 511;
  float acc = prev ? prev[i] : 0.f;
  const float* pp = partial + (size_t)b * 32 * DD + d;
#pragma unroll
  for (int c = 0; c < 32; ++c) acc += pp[c * DD];
  uout[i] = acc;
}

// ---- stage B, decoder hop0: o0 = sum partials; uk = hid + o0; hc = [hid | o0]
__global__ void wsumB2_kernel(const float* __restrict__ partial,
                              const float* __restrict__ hid,
                              float* __restrict__ uk, float* __restrict__ hc) {
  int i = blockIdx.x * 256 + threadIdx.x;
  int b = i >> 9, d = i & 511;
  float ov = 0.f;
  const float* pp = partial + (size_t)b * 32 * DD + d;
#pragma unroll
  for (int c = 0; c < 32; ++c) ov += pp[c * DD];
  float hv = hid[i];
  uk[i] = hv + ov;
  hc[b * 1024 + d] = hv;
  hc[b * 1024 + 512 + d] = ov;
}

// ---- fused gather + dot (for dot-only table D0): one wave per (b,m).
__global__ __launch_bounds__(256) void pooldot_kernel(const float* __restrict__ table,
                                                      const int* __restrict__ story,
                                                      const float* __restrict__ u,
                                                      float* __restrict__ s) {
  int wave = (blockIdx.x << 2) + (threadIdx.x >> 6);
  int lane = threadIdx.x & 63;
  int b = wave >> 9;
  const int* st = story + wave * TT;
  size_t r0 = (size_t)st[0] * DD, r1 = (size_t)st[1] * DD;
  size_t r2 = (size_t)st[2] * DD, r3 = (size_t)st[3] * DD;
  const float4* t4 = (const float4*)table;
  const float4* ur = (const float4*)(u + (size_t)b * DD);
  float acc = 0.f;
#pragma unroll
  for (int h = 0; h < 2; ++h) {
    int c = (h << 6) + lane;
    float4 a = t4[(r0 >> 2) + c];
    float4 bb = t4[(r1 >> 2) + c];
    float4 cc = t4[(r2 >> 2) + c];
    float4 d = t4[(r3 >> 2) + c];
    float4 q = ur[c];
    acc += (a.x + bb.x + cc.x + d.x) * q.x;
    acc += (a.y + bb.y + cc.y + d.y) * q.y;
    acc += (a.z + bb.z + cc.z + d.z) * q.z;
    acc += (a.w + bb.w + cc.w + d.w) * q.w;
  }
#pragma unroll
  for (int off = 32; off > 0; off >>= 1) acc += __shfl_xor(acc, off);
  if (lane == 0) s[wave] = acc;
}

// ---- both GRU matvecs in one launch. Grid 2*mvGrid:
// first half: gi[b][j] = b_ih[j] + W_ih[j] . C_dec[q[b]]
// second half: gh[b][j] = b_hh[j] + W_hh[j] . u[b]
__global__ __launch_bounds__(256) void matvec2_kernel(const float* __restrict__ W_ih,
                                                      const float* __restrict__ b_ih,
                                                      const float* __restrict__ W_hh,
                                                      const float* __restrict__ b_hh,
                                                      const int* __restrict__ q,
                                                      const float* __restrict__ Cdec,
                                                      const float* __restrict__ u,
                                                      float* __restrict__ gi,
                                                      float* __restrict__ gh,
                                                      int mvGrid) {
  int half = blockIdx.x >= mvGrid;
  int bid = blockIdx.x - (half ? mvGrid : 0);
  int idx = (bid << 2) + (threadIdx.x >> 6);  // b*1536 + j
  int lane = threadIdx.x & 63;
  int b = idx / 1536;
  int j = idx - b * 1536;
  const float* W = half ? W_hh : W_ih;
  const float* bias = half ? b_hh : b_ih;
  const float* xb = half ? (u + (size_t)b * DD) : (Cdec + (size_t)q[b] * DD);
  float* outp = half ? gh : gi;
  const float4* Wr = (const float4*)(W + (size_t)j * DD);
  const float4* xr = (const float4*)xb;
  float acc = 0.f;
#pragma unroll
  for (int h = 0; h < 2; ++h) {
    int c = (h << 6) + lane;
    float4 a = Wr[c];
    float4 qv = xr[c];
    acc += a.x * qv.x + a.y * qv.y + a.z * qv.z + a.w * qv.w;
  }
#pragma unroll
  for (int off = 32; off > 0; off >>= 1) acc += __shfl_xor(acc, off);
  if (lane == 0) outp[idx] = acc + bias[j];
}

// ---- GRU gates: hidden = (1-z)*n + z*u
__global__ void gate_kernel(const float* __restrict__ gi, const float* __restrict__ gh,
                            const float* __restrict__ u, float* __restrict__ hidden,
                            float* __restrict__ out_h) {
  int i = blockIdx.x * 256 + threadIdx.x;  // B*D
  int b = i >> 9, d = i & 511;
  const float* gib = gi + b * 1536;
  const float* ghb = gh + b * 1536;
  float i_r = gib[d], i_z = gib[d + 512], i_n = gib[d + 1024];
  float h_r = ghb[d], h_z = ghb[d + 512], h_n = ghb[d + 1024];
  float r = 1.f / (1.f + expf(-(i_r + h_r)));
  float z = 1.f / (1.f + expf(-(i_z + h_z)));
  float n = tanhf(i_n + r * h_n);
  float h = (1.f - z) * n + z * u[i];
  hidden[i] = h;
  out_h[i] = h;
}

// ---- p_vocab partials, split-K x2, ping-pong LDS (1 sync per chunk).
__global__ __launch_bounds__(256) void pvocab_kernel(const float* __restrict__ Hcat,
                                                     const float* __restrict__ W1,
                                                     float* __restrict__ partc) {
  __shared__ float As[2][32][36];
  __shared__ float Bs[2][32][68];
  int t = threadIdx.x;
  int vt = blockIdx.x >> 1;
  int kh = blockIdx.x & 1;
  int v0 = vt * 64;
  int kbase = kh << 9;            // 0 or 512
  int tb = t >> 5;
  int tv = t & 31;
  int br = t >> 2;
  int bk = (t & 3) << 3;
  const float* Wp = W1 + (size_t)(v0 + br) * 1024 + kbase + bk;
  int ab = t >> 3;
  int ak = (t & 7) << 2;
  const float* Ap = Hcat + (size_t)ab * 1024 + kbase + ak;

  float acc[4][2] = {{0.f, 0.f}, {0.f, 0.f}, {0.f, 0.f}, {0.f, 0.f}};

  float4 aReg = *(const float4*)(Ap);
  float4 wReg0 = *(const float4*)(Wp);
  float4 wReg1 = *(const float4*)(Wp + 4);

  for (int ci = 0; ci < 16; ++ci) {
    int buf = ci & 1;
    // store staged regs for this chunk
    As[buf][ak + 0][ab] = aReg.x; As[buf][ak + 1][ab] = aReg.y;
    As[buf][ak + 2][ab] = aReg.z; As[buf][ak + 3][ab] = aReg.w;
    Bs[buf][bk + 0][br] = wReg0.x; Bs[buf][bk + 1][br] = wReg0.y;
    Bs[buf][bk + 2][br] = wReg0.z; Bs[buf][bk + 3][br] = wReg0.w;
    Bs[buf][bk + 4][br] = wReg1.x; Bs[buf][bk + 5][br] = wReg1.y;
    Bs[buf][bk + 6][br] = wReg1.z; Bs[buf][bk + 7][br] = wReg1.w;
    __syncthreads();                 // single barrier per chunk (ping-pong safe)
    if (ci < 15) {                   // issue next chunk's loads immediately
      int k0 = (ci + 1) << 5;
      aReg = *(const float4*)(Ap + k0);
      wReg0 = *(const float4*)(Wp + k0);
      wReg1 = *(const float4*)(Wp + k0 + 4);
    }
#pragma unroll
    for (int k = 0; k < 32; ++k) {
      float2 bv = *(const float2*)&Bs[buf][k][tv * 2];
      float4 av = *(const float4*)&As[buf][k][tb * 4];
      acc[0][0] += av.x * bv.x; acc[0][1] += av.x * bv.y;
      acc[1][0] += av.y * bv.x; acc[1][1] += av.y * bv.y;
      acc[2][0] += av.z * bv.x; acc[2][1] += av.z * bv.y;
      acc[3][0] += av.w * bv.x; acc[3][1] += av.w * bv.y;
    }
  }
  int v = v0 + tv * 2;
  float* base = partc + (size_t)kh * BV;
#pragma unroll
  for (int i = 0; i < 4; ++i) {
    float2 r;
    r.x = acc[i][0];
    r.y = acc[i][1];
    *(float2*)(base + (size_t)(tb * 4 + i) * VV + v) = r;
  }
}

// ---- out[b][v] = partc[0][b][v] + partc[1][b][v] + W1b[v].  grid (125, 32).
__global__ void pvreduce_kernel(const float* __restrict__ partc,
                                const float* __restrict__ W1b,
                                float* __restrict__ out) {
  int v = blockIdx.x * 256 + threadIdx.x;   // 125*256 = 32000
  int b = blockIdx.y;
  size_t o = (size_t)b * VV + v;
  out[o] = partc[o] + partc[BV + o] + W1b[v];
}

extern "C" void kernel_launch(void* const* d_in, const int* in_sizes, int n_in,
                              void* d_out, int out_size, void* d_ws, size_t ws_size,
                              hipStream_t stream) {
  const int* story = (const int*)d_in[0];
  const int* q = (const int*)d_in[1];
  const float* C_enc = (const float*)d_in[2];
  const float* C_dec = (const float*)d_in[3];
  const float* W_ih = (const float*)d_in[4];
  const float* W_hh = (const float*)d_in[5];
  const float* b_ih = (const float*)d_in[6];
  const float* b_hh = (const float*)d_in[7];
  const float* W1 = (const float*)d_in[8];
  const float* W1b = (const float*)d_in[9];
  float* out = (float*)d_out;

  const size_t VD = (size_t)VV * DD;
  const float* C1 = C_enc + 1 * VD;
  const float* C2 = C_enc + 2 * VD;
  const float* C3 = C_enc + 3 * VD;
  const float* D0 = C_dec + 0 * VD;
  const float* D1 = C_dec + 1 * VD;
  const float* D2 = C_dec + 2 * VD;

  float* P = (float*)d_ws;                         // [B*M*D] materialized pool
  float* part = P + (size_t)BB * MM * DD;          // [B*32*D]
  float* partc = part + (size_t)BB * 32 * DD;      // [2*B*V]
  float* u = partc + 2 * BV;                       // [B*D]
  float* s = u + BB * DD;                          // [B*M]
  float* gi = s + BB * MM;                         // [B*3D]
  float* gh = gi + BB * 3 * DD;                    // [B*3D]
  float* hid = gh + BB * 3 * DD;                   // [B*D]
  float* uk = hid + BB * DD;                       // [B*D]
  float* hc = uk + BB * DD;                        // [B*2D]

  float* p_ptr_out = out;
  float* p_vocab_out = out + BB * MM;
  float* hid_out = out + BB * MM + (size_t)BB * VV;

  dim3 blk(256);
  const int pwGrid = BB * 32;          // 1024 blocks
  const int pdGrid = BB * MM / 4;      // 4096 blocks (pooldot)
  const int PdGrid = BB * 32;          // 1024 blocks (Pdot)
  const int mvGrid = BB * 3 * DD / 4;  // 3072 blocks per matvec
  const int ewGrid = BB * DD / 256;    // 64

  // ---------------- encoder (u0 = 0 => hop0 softmax uniform; C_enc[0] unused)
  poolwsumP_kernel<<<pwGrid, blk, 0, stream>>>(C1, story, nullptr, P, part);
  wsumB_kernel<<<ewGrid, blk, 0, stream>>>(part, nullptr, u);      // u1 = mean pool
  Pdot_kernel<<<PdGrid, blk, 0, stream>>>(P, u, s);                // s1 (stream over P)
  poolwsumP_kernel<<<pwGrid, blk, 0, stream>>>(C2, story, s, P, part);
  wsumB_kernel<<<ewGrid, blk, 0, stream>>>(part, u, u);            // u2
  Pdot_kernel<<<PdGrid, blk, 0, stream>>>(P, u, s);                // s2
  poolwsumP_kernel<<<pwGrid, blk, 0, stream>>>(C3, story, s, nullptr, part);  // no P
  wsumB_kernel<<<ewGrid, blk, 0, stream>>>(part, u, u);            // u3 = enc_hidden

  // ---------------- GRU step (both matvecs in one launch)
  matvec2_kernel<<<2 * mvGrid, blk, 0, stream>>>(W_ih, b_ih, W_hh, b_hh, q, C_dec, u,
                                                 gi, gh, mvGrid);
  gate_kernel<<<ewGrid, blk, 0, stream>>>(gi, gh, u, hid, hid_out);

  // ---------------- pointer decoder (C_dec[3] pooled is dead code)
  pooldot_kernel<<<pdGrid, blk, 0, stream>>>(D0, story, hid, s);   // hop0 logits (gather)
  poolwsumP_kernel<<<pwGrid, blk, 0, stream>>>(D1, story, s, P, part);
  wsumB2_kernel<<<ewGrid, blk, 0, stream>>>(part, hid, uk, hc);    // o0, uk1, hcat
  Pdot_kernel<<<PdGrid, blk, 0, stream>>>(P, uk, s);               // hop1 logits
  poolwsumP_kernel<<<pwGrid, blk, 0, stream>>>(D2, story, s, P, part);
  wsumB_kernel<<<ewGrid, blk, 0, stream>>>(part, uk, uk);          // uk2
  Pdot_kernel<<<PdGrid, blk, 0, stream>>>(P, uk, p_ptr_out);       // p_ptr

  // ---------------- vocab projection (split-K x2 + reduce)
  pvocab_kernel<<<VV / 64 * 2, blk, 0, stream>>>(hc, W1, partc);
  pvreduce_kernel<<<dim3(125, 32), blk, 0, stream>>>(partc, W1b, p_vocab_out);
}

// Round 13
// 263.239 us; speedup vs baseline: 2.0206x; 1.0116x over previous
//
#include <hip/hip_runtime.h>
#include <math.h>

#define DD 512
#define MM 512
#define BB 32
#define TT 4
#define VV 32000
#define BV ((size_t)BB * VV)

// ---- fused gather + softmax-weighted partial sum + optional P materialization.
// block = b*32 + c (c = 16-m chunk). Gathers 64 story rows, pools per-m (4 rows),
// optionally writes pooled row to P[b][m][:], accumulates w[m]*pooled into partial.
// w = softmax(s[b]) computed redundantly per block; s==null -> 1/M.
__global__ __launch_bounds__(256) void poolwsumP_kernel(const float* __restrict__ table,
                                                        const int* __restrict__ story,
                                                        const float* __restrict__ s,
                                                        float* __restrict__ P,
                                                        float* __restrict__ partial) {
  __shared__ float wrow[16];
  __shared__ int rows[64];
  __shared__ float red[16];
  __shared__ float4 comb[128];
  int b = blockIdx.x >> 5;
  int c = blockIdx.x & 31;
  int t = threadIdx.x;
  if (s) {
    float v0 = s[b * MM + t], v1 = s[b * MM + t + 256];
    float mx = fmaxf(v0, v1);
#pragma unroll
    for (int off = 32; off > 0; off >>= 1) mx = fmaxf(mx, __shfl_xor(mx, off));
    if ((t & 63) == 0) red[t >> 6] = mx;
    __syncthreads();
    mx = fmaxf(fmaxf(red[0], red[1]), fmaxf(red[2], red[3]));
    float e0 = expf(v0 - mx), e1 = expf(v1 - mx);
    float sm = e0 + e1;
#pragma unroll
    for (int off = 32; off > 0; off >>= 1) sm += __shfl_xor(sm, off);
    if ((t & 63) == 0) red[8 + (t >> 6)] = sm;
    __syncthreads();
    sm = red[8] + red[9] + red[10] + red[11];
    float inv = 1.0f / sm;
    if (t < 16) wrow[t] = expf(s[b * MM + (c << 4) + t] - mx) * inv;
  } else {
    if (t < 16) wrow[t] = 1.0f / MM;
  }
  if (t < 64) rows[t] = story[((b << 9) + (c << 4)) * TT + t];
  __syncthreads();
  int h = t >> 7;             // half: 0 or 1
  int col = t & 127;          // float4 column
  float4 acc = make_float4(0.f, 0.f, 0.f, 0.f);
#pragma unroll
  for (int i = 0; i < 8; ++i) {
    int lm = (i << 1) + h;    // local m, half-interleaved
    const float4* r0 = (const float4*)(table + (size_t)rows[lm * 4 + 0] * DD);
    const float4* r1 = (const float4*)(table + (size_t)rows[lm * 4 + 1] * DD);
    const float4* r2 = (const float4*)(table + (size_t)rows[lm * 4 + 2] * DD);
    const float4* r3 = (const float4*)(table + (size_t)rows[lm * 4 + 3] * DD);
    float4 a = r0[col], bb = r1[col], cc = r2[col], d = r3[col];
    float4 pooled;
    pooled.x = a.x + bb.x + cc.x + d.x;
    pooled.y = a.y + bb.y + cc.y + d.y;
    pooled.z = a.z + bb.z + cc.z + d.z;
    pooled.w = a.w + bb.w + cc.w + d.w;
    if (P) ((float4*)(P + ((size_t)(b << 9) + (c << 4) + lm) * DD))[col] = pooled;
    float wm = wrow[lm];
    acc.x += wm * pooled.x; acc.y += wm * pooled.y;
    acc.z += wm * pooled.z; acc.w += wm * pooled.w;
  }
  if (h) comb[col] = acc;
  __syncthreads();
  if (!h) {
    float4 o = comb[col];
    acc.x += o.x; acc.y += o.y; acc.z += o.z; acc.w += o.w;
    ((float4*)(partial + (size_t)blockIdx.x * DD))[col] = acc;
  }
}

// ---- stream dot over materialized P: s[b][m] = P[b][m][:] . u[b][:].
__global__ __launch_bounds__(256) void Pdot_kernel(const float* __restrict__ P,
                                                   const float* __restrict__ u,
                                                   float* __restrict__ s) {
  int b = blockIdx.x >> 5;
  int c = blockIdx.x & 31;
  int w = threadIdx.x >> 6;
  int lane = threadIdx.x & 63;
  const float4* ur = (const float4*)(u + (size_t)b * DD);
  float4 u0 = ur[lane], u1 = ur[lane + 64];
  const float4* Pb = (const float4*)(P + ((size_t)(b << 9) + (c << 4)) * DD);
#pragma unroll
  for (int j = 0; j < 4; ++j) {
    int m = (w << 2) + j;     // local m 0..15
    const float4* pr = Pb + (size_t)m * 128;
    float4 a = pr[lane], bb = pr[lane + 64];
    float acc = a.x * u0.x + a.y * u0.y + a.z * u0.z + a.w * u0.w
              + bb.x * u1.x + bb.y * u1.y + bb.z * u1.z + bb.w * u1.w;
#pragma unroll
    for (int off = 32; off > 0; off >>= 1) acc += __shfl_xor(acc, off);
    if (lane == 0) s[(b << 9) + (c << 4) + m] = acc;
  }
}

// ---- stage B: uout[b][d] = (prev ? prev[b][d] : 0) + sum_{c<32} partial[b*32+c][d]
__global__ void wsumB_kernel(const float* __restrict__ partial,
                             const float* __restrict__ prev,
                             float* __restrict__ uout) {
  int i = blockIdx.x * 256 + threadIdx.x;   // 64 blocks -> B*D
  int b = i >> 9, d = i & 511;
  float acc = prev ? prev[i] : 0.f;
  const float* pp = partial + (size_t)b * 32 * DD + d;
#pragma unroll
  for (int c = 0; c < 32; ++c) acc += pp[c * DD];
  uout[i] = acc;
}

// ---- stage B, decoder hop0: o0 = sum partials; uk = hid + o0; hc = [hid | o0]
__global__ void wsumB2_kernel(const float* __restrict__ partial,
                              const float* __restrict__ hid,
                              float* __restrict__ uk, float* __restrict__ hc) {
  int i = blockIdx.x * 256 + threadIdx.x;
  int b = i >> 9, d = i & 511;
  float ov = 0.f;
  const float* pp = partial + (size_t)b * 32 * DD + d;
#pragma unroll
  for (int c = 0; c < 32; ++c) ov += pp[c * DD];
  float hv = hid[i];
  uk[i] = hv + ov;
  hc[b * 1024 + d] = hv;
  hc[b * 1024 + 512 + d] = ov;
}

// ---- fused gather + dot (for dot-only table D0): one wave per (b,m).
__global__ __launch_bounds__(256) void pooldot_kernel(const float* __restrict__ table,
                                                      const int* __restrict__ story,
                                                      const float* __restrict__ u,
                                                      float* __restrict__ s) {
  int wave = (blockIdx.x << 2) + (threadIdx.x >> 6);
  int lane = threadIdx.x & 63;
  int b = wave >> 9;
  const int* st = story + wave * TT;
  size_t r0 = (size_t)st[0] * DD, r1 = (size_t)st[1] * DD;
  size_t r2 = (size_t)st[2] * DD, r3 = (size_t)st[3] * DD;
  const float4* t4 = (const float4*)table;
  const float4* ur = (const float4*)(u + (size_t)b * DD);
  float acc = 0.f;
#pragma unroll
  for (int h = 0; h < 2; ++h) {
    int c = (h << 6) + lane;
    float4 a = t4[(r0 >> 2) + c];
    float4 bb = t4[(r1 >> 2) + c];
    float4 cc = t4[(r2 >> 2) + c];
    float4 d = t4[(r3 >> 2) + c];
    float4 q = ur[c];
    acc += (a.x + bb.x + cc.x + d.x) * q.x;
    acc += (a.y + bb.y + cc.y + d.y) * q.y;
    acc += (a.z + bb.z + cc.z + d.z) * q.z;
    acc += (a.w + bb.w + cc.w + d.w) * q.w;
  }
#pragma unroll
  for (int off = 32; off > 0; off >>= 1) acc += __shfl_xor(acc, off);
  if (lane == 0) s[wave] = acc;
}

// ---- both GRU matvecs in one launch. Grid 2*mvGrid.
__global__ __launch_bounds__(256) void matvec2_kernel(const float* __restrict__ W_ih,
                                                      const float* __restrict__ b_ih,
                                                      const float* __restrict__ W_hh,
                                                      const float* __restrict__ b_hh,
                                                      const int* __restrict__ q,
                                                      const float* __restrict__ Cdec,
                                                      const float* __restrict__ u,
                                                      float* __restrict__ gi,
                                                      float* __restrict__ gh,
                                                      int mvGrid) {
  int half = blockIdx.x >= mvGrid;
  int bid = blockIdx.x - (half ? mvGrid : 0);
  int idx = (bid << 2) + (threadIdx.x >> 6);  // b*1536 + j
  int lane = threadIdx.x & 63;
  int b = idx / 1536;
  int j = idx - b * 1536;
  const float* W = half ? W_hh : W_ih;
  const float* bias = half ? b_hh : b_ih;
  const float* xb = half ? (u + (size_t)b * DD) : (Cdec + (size_t)q[b] * DD);
  float* outp = half ? gh : gi;
  const float4* Wr = (const float4*)(W + (size_t)j * DD);
  const float4* xr = (const float4*)xb;
  float acc = 0.f;
#pragma unroll
  for (int h = 0; h < 2; ++h) {
    int c = (h << 6) + lane;
    float4 a = Wr[c];
    float4 qv = xr[c];
    acc += a.x * qv.x + a.y * qv.y + a.z * qv.z + a.w * qv.w;
  }
#pragma unroll
  for (int off = 32; off > 0; off >>= 1) acc += __shfl_xor(acc, off);
  if (lane == 0) outp[idx] = acc + bias[j];
}

// ---- GRU gates: hidden = (1-z)*n + z*u
__global__ void gate_kernel(const float* __restrict__ gi, const float* __restrict__ gh,
                            const float* __restrict__ u, float* __restrict__ hidden,
                            float* __restrict__ out_h) {
  int i = blockIdx.x * 256 + threadIdx.x;  // B*D
  int b = i >> 9, d = i & 511;
  const float* gib = gi + b * 1536;
  const float* ghb = gh + b * 1536;
  float i_r = gib[d], i_z = gib[d + 512], i_n = gib[d + 1024];
  float h_r = ghb[d], h_z = ghb[d + 512], h_n = ghb[d + 1024];
  float r = 1.f / (1.f + expf(-(i_r + h_r)));
  float z = 1.f / (1.f + expf(-(i_z + h_z)));
  float n = tanhf(i_n + r * h_n);
  float h = (1.f - z) * n + z * u[i];
  hidden[i] = h;
  out_h[i] = h;
}

// ---- p_vocab single-pass: out[b][v] = Hcat[b][:].W1[v][:] + W1b[v].
// 500 blocks (64-v tile, full K=1024), ping-pong LDS, one sync per 32-K chunk,
// bias folded, direct write to output (no partials round-trip).
__global__ __launch_bounds__(256) void pvocab_kernel(const float* __restrict__ Hcat,
                                                     const float* __restrict__ W1,
                                                     const float* __restrict__ W1b,
                                                     float* __restrict__ out) {
  __shared__ float As[2][32][36];
  __shared__ float Bs[2][32][68];
  int t = threadIdx.x;
  int v0 = blockIdx.x * 64;
  int tb = t >> 5;
  int tv = t & 31;
  int br = t >> 2;
  int bk = (t & 3) << 3;
  const float* Wp = W1 + (size_t)(v0 + br) * 1024 + bk;
  int ab = t >> 3;
  int ak = (t & 7) << 2;
  const float* Ap = Hcat + (size_t)ab * 1024 + ak;

  float acc[4][2] = {{0.f, 0.f}, {0.f, 0.f}, {0.f, 0.f}, {0.f, 0.f}};

  float4 aReg = *(const float4*)(Ap);
  float4 wReg0 = *(const float4*)(Wp);
  float4 wReg1 = *(const float4*)(Wp + 4);

  for (int ci = 0; ci < 32; ++ci) {
    int buf = ci & 1;
    As[buf][ak + 0][ab] = aReg.x; As[buf][ak + 1][ab] = aReg.y;
    As[buf][ak + 2][ab] = aReg.z; As[buf][ak + 3][ab] = aReg.w;
    Bs[buf][bk + 0][br] = wReg0.x; Bs[buf][bk + 1][br] = wReg0.y;
    Bs[buf][bk + 2][br] = wReg0.z; Bs[buf][bk + 3][br] = wReg0.w;
    Bs[buf][bk + 4][br] = wReg1.x; Bs[buf][bk + 5][br] = wReg1.y;
    Bs[buf][bk + 6][br] = wReg1.z; Bs[buf][bk + 7][br] = wReg1.w;
    __syncthreads();                 // single barrier per chunk (ping-pong safe)
    if (ci < 31) {                   // issue next chunk's loads immediately
      int k0 = (ci + 1) << 5;
      aReg = *(const float4*)(Ap + k0);
      wReg0 = *(const float4*)(Wp + k0);
      wReg1 = *(const float4*)(Wp + k0 + 4);
    }
#pragma unroll
    for (int k = 0; k < 32; ++k) {
      float2 bv = *(const float2*)&Bs[buf][k][tv * 2];
      float4 av = *(const float4*)&As[buf][k][tb * 4];
      acc[0][0] += av.x * bv.x; acc[0][1] += av.x * bv.y;
      acc[1][0] += av.y * bv.x; acc[1][1] += av.y * bv.y;
      acc[2][0] += av.z * bv.x; acc[2][1] += av.z * bv.y;
      acc[3][0] += av.w * bv.x; acc[3][1] += av.w * bv.y;
    }
  }
  int v = v0 + tv * 2;
  float b0 = W1b[v], b1 = W1b[v + 1];
#pragma unroll
  for (int i = 0; i < 4; ++i) {
    float2 r;
    r.x = acc[i][0] + b0;
    r.y = acc[i][1] + b1;
    *(float2*)(out + (size_t)(tb * 4 + i) * VV + v) = r;
  }
}

extern "C" void kernel_launch(void* const* d_in, const int* in_sizes, int n_in,
                              void* d_out, int out_size, void* d_ws, size_t ws_size,
                              hipStream_t stream) {
  const int* story = (const int*)d_in[0];
  const int* q = (const int*)d_in[1];
  const float* C_enc = (const float*)d_in[2];
  const float* C_dec = (const float*)d_in[3];
  const float* W_ih = (const float*)d_in[4];
  const float* W_hh = (const float*)d_in[5];
  const float* b_ih = (const float*)d_in[6];
  const float* b_hh = (const float*)d_in[7];
  const float* W1 = (const float*)d_in[8];
  const float* W1b = (const float*)d_in[9];
  float* out = (float*)d_out;

  const size_t VD = (size_t)VV * DD;
  const float* C1 = C_enc + 1 * VD;
  const float* C2 = C_enc + 2 * VD;
  const float* C3 = C_enc + 3 * VD;
  const float* D0 = C_dec + 0 * VD;
  const float* D1 = C_dec + 1 * VD;
  const float* D2 = C_dec + 2 * VD;

  float* P = (float*)d_ws;                         // [B*M*D] materialized pool
  float* part = P + (size_t)BB * MM * DD;          // [B*32*D]
  float* u = part + (size_t)BB * 32 * DD;          // [B*D]
  float* s = u + BB * DD;                          // [B*M]
  float* gi = s + BB * MM;                         // [B*3D]
  float* gh = gi + BB * 3 * DD;                    // [B*3D]
  float* hid = gh + BB * 3 * DD;                   // [B*D]
  float* uk = hid + BB * DD;                       // [B*D]
  float* hc = uk + BB * DD;                        // [B*2D]

  float* p_ptr_out = out;
  float* p_vocab_out = out + BB * MM;
  float* hid_out = out + BB * MM + (size_t)BB * VV;

  dim3 blk(256);
  const int pwGrid = BB * 32;          // 1024 blocks
  const int pdGrid = BB * MM / 4;      // 4096 blocks (pooldot)
  const int PdGrid = BB * 32;          // 1024 blocks (Pdot)
  const int mvGrid = BB * 3 * DD / 4;  // 3072 blocks per matvec
  const int ewGrid = BB * DD / 256;    // 64

  // ---------------- encoder (u0 = 0 => hop0 softmax uniform; C_enc[0] unused)
  poolwsumP_kernel<<<pwGrid, blk, 0, stream>>>(C1, story, nullptr, P, part);
  wsumB_kernel<<<ewGrid, blk, 0, stream>>>(part, nullptr, u);      // u1 = mean pool
  Pdot_kernel<<<PdGrid, blk, 0, stream>>>(P, u, s);                // s1 (stream over P)
  poolwsumP_kernel<<<pwGrid, blk, 0, stream>>>(C2, story, s, P, part);
  wsumB_kernel<<<ewGrid, blk, 0, stream>>>(part, u, u);            // u2
  Pdot_kernel<<<PdGrid, blk, 0, stream>>>(P, u, s);                // s2
  poolwsumP_kernel<<<pwGrid, blk, 0, stream>>>(C3, story, s, nullptr, part);  // no P
  wsumB_kernel<<<ewGrid, blk, 0, stream>>>(part, u, u);            // u3 = enc_hidden

  // ---------------- GRU step (both matvecs in one launch)
  matvec2_kernel<<<2 * mvGrid, blk, 0, stream>>>(W_ih, b_ih, W_hh, b_hh, q, C_dec, u,
                                                 gi, gh, mvGrid);
  gate_kernel<<<ewGrid, blk, 0, stream>>>(gi, gh, u, hid, hid_out);

  // ---------------- pointer decoder (C_dec[3] pooled is dead code)
  pooldot_kernel<<<pdGrid, blk, 0, stream>>>(D0, story, hid, s);   // hop0 logits (gather)
  poolwsumP_kernel<<<pwGrid, blk, 0, stream>>>(D1, story, s, P, part);
  wsumB2_kernel<<<ewGrid, blk, 0, stream>>>(part, hid, uk, hc);    // o0, uk1, hcat
  Pdot_kernel<<<PdGrid, blk, 0, stream>>>(P, uk, s);               // hop1 logits
  poolwsumP_kernel<<<pwGrid, blk, 0, stream>>>(D2, story, s, P, part);
  wsumB_kernel<<<ewGrid, blk, 0, stream>>>(part, uk, uk);          // uk2
  Pdot_kernel<<<PdGrid, blk, 0, stream>>>(P, uk, p_ptr_out);       // p_ptr

  // ---------------- vocab projection (single pass, direct write)
  pvocab_kernel<<<VV / 64, blk, 0, stream>>>(hc, W1, W1b, p_vocab_out);
}